// Round 2
// baseline (15816.972 us; speedup 1.0000x reference)
//
#include <hip/hip_runtime.h>
#include <stdint.h>
#include <math.h>

typedef unsigned short u16;
typedef short s16x8 __attribute__((ext_vector_type(8)));
typedef __bf16 bv8 __attribute__((ext_vector_type(8)));
typedef float f32x4 __attribute__((ext_vector_type(4)));

#define DEV static __device__ __forceinline__

DEV float b2f(u16 x){ union{unsigned u; float f;} v; v.u=((unsigned)x)<<16; return v.f; }
DEV u16 f2b(float f){ union{float f; unsigned u;} v; v.f=f; unsigned u=v.u; u += 0x7fff + ((u>>16)&1u); return (u16)(u>>16); }
DEV float sigm(float x){ return 1.f/(1.f+expf(-x)); }
DEV f32x4 mfma16(bv8 a, bv8 b, f32x4 c){ return __builtin_amdgcn_mfma_f32_16x16x32_bf16(a,b,c,0,0,0); }
DEV bv8 ldf(const u16* p){ return __builtin_bit_cast(bv8, *(const s16x8*)p); }

// ---------------- weight f32 -> bf16 conversion (14 arrays, one launch) ----------------
struct CvtJobs { const float* s[14]; u16* d[14]; int start[14]; };

__global__ __launch_bounds__(256) void cvt_w(CvtJobs J){
  int blk = blockIdx.x, tid = threadIdx.x;
  int j = 0;
  #pragma unroll
  for (int k=1;k<14;k++) if (blk >= J.start[k]) j = k;
  size_t idx = (size_t)(blk - J.start[j])*2048 + (size_t)tid*8;
  const f32x4* ps = (const f32x4*)(J.s[j] + idx);
  f32x4 a = ps[0], b = ps[1];
  s16x8 o;
  #pragma unroll
  for (int i=0;i<4;i++){ o[i]=(short)f2b(a[i]); o[4+i]=(short)f2b(b[i]); }
  *(s16x8*)(J.d[j] + idx) = o;
}

// ---------------- LayerNorm stats: mean/rstd over [T*DIM]=32768 per sample ----------------
__global__ __launch_bounds__(256) void ln_stats(const float* __restrict__ x,
                                                float* __restrict__ mu, float* __restrict__ rstd){
  int b = blockIdx.x;
  const float* xb = x + (size_t)b*32768;
  float s1=0.f, s2=0.f;
  for (int i = threadIdx.x*4; i < 32768; i += 256*4){
    f32x4 v = *(const f32x4*)(xb+i);
    #pragma unroll
    for (int j=0;j<4;j++){ float f = v[j]; s1+=f; s2+=f*f; }
  }
  #pragma unroll
  for (int o=32;o>0;o>>=1){ s1 += __shfl_down(s1,o); s2 += __shfl_down(s2,o); }
  __shared__ float r1[4], r2[4];
  int w = threadIdx.x>>6;
  if ((threadIdx.x&63)==0){ r1[w]=s1; r2[w]=s2; }
  __syncthreads();
  if (threadIdx.x==0){
    float a=0.f,c=0.f;
    for (int i=0;i<4;i++){ a+=r1[i]; c+=r2[i]; }
    float m=a/32768.f, v=c/32768.f-m*m;
    mu[b]=m; rstd[b]=1.f/sqrtf(v+1e-5f);
  }
}

// ---------------- fused LN + encode GEMM: xe[131072,256] = relu(LN(x) @ We^T + be) ----------------
// BM=128, BN=128, K=128, grid (2, 1024)
__global__ __launch_bounds__(256) void ln_gemm(const float* __restrict__ x,
    const float* __restrict__ mu, const float* __restrict__ rstd,
    const float* __restrict__ g, const float* __restrict__ bn,
    const u16* __restrict__ Wb, const float* __restrict__ be, u16* __restrict__ xe){
  __shared__ __align__(16) u16 As[128*32];
  __shared__ __align__(16) u16 Ws[128*32];
  int tid=threadIdx.x, lane=tid&63, wid=tid>>6;
  int wr=wid>>1, wc=wid&1;
  long m0=(long)blockIdx.y*128, n0=(long)blockIdx.x*128;
  int lr=lane&15, lk=(lane>>4)*8;
  f32x4 acc[4][4];
  #pragma unroll
  for (int i=0;i<4;i++)
    #pragma unroll
    for (int j=0;j<4;j++) acc[i][j]=(f32x4){0.f,0.f,0.f,0.f};

  for (int k0=0;k0<128;k0+=32){
    __syncthreads();
    #pragma unroll
    for (int c=tid;c<512;c+=256){
      int row=c>>2, kb=(c&3)*8;
      long R=m0+row;
      int b=(int)(R>>8), tt=(int)(R&255);
      float m=mu[b], rs=rstd[b];
      const f32x4* px=(const f32x4*)(x + R*128 + k0+kb);
      const f32x4* pg=(const f32x4*)(g + tt*128 + k0+kb);
      const f32x4* pb=(const f32x4*)(bn + tt*128 + k0+kb);
      f32x4 x0=px[0], x1=px[1], g0=pg[0], g1=pg[1], b0=pb[0], b1=pb[1];
      s16x8 o;
      #pragma unroll
      for (int j=0;j<4;j++){
        o[j]   = (short)f2b((x0[j]-m)*rs*g0[j] + b0[j]);
        o[4+j] = (short)f2b((x1[j]-m)*rs*g1[j] + b1[j]);
      }
      *(s16x8*)(As + row*32 + kb) = o;
    }
    #pragma unroll
    for (int c=tid;c<512;c+=256){
      int row=c>>2, kb=(c&3)*8;
      *(s16x8*)(Ws + row*32 + kb) = *(const s16x8*)(Wb + (n0+row)*128 + k0+kb);
    }
    __syncthreads();
    bv8 af[4], bf[4];
    #pragma unroll
    for (int i=0;i<4;i++) af[i] = ldf(As + (wr*64+i*16+lr)*32 + lk);
    #pragma unroll
    for (int j=0;j<4;j++) bf[j] = ldf(Ws + (wc*64+j*16+lr)*32 + lk);
    #pragma unroll
    for (int i=0;i<4;i++)
      #pragma unroll
      for (int j=0;j<4;j++) acc[i][j] = mfma16(af[i], bf[j], acc[i][j]);
  }
  #pragma unroll
  for (int i=0;i<4;i++)
    #pragma unroll
    for (int j=0;j<4;j++)
      #pragma unroll
      for (int r=0;r<4;r++){
        int m = wr*64+i*16+(lane>>4)*4+r;
        int n = wc*64+j*16+lr;
        float v = acc[i][j][r] + be[n0+n];
        xe[(m0+m)*256 + n0+n] = f2b(fmaxf(v,0.f));
      }
}

// ---------------- generic GEMM: C[M,N] = act(A[M,K](bf16) @ W[N,K](bf16)^T + b1 + b2) ----------------
template<int BM, int BN, bool RELU, bool OUTF32>
__global__ __launch_bounds__(256) void gemm_bt(const u16* __restrict__ A, int lda,
                                               const u16* __restrict__ W, int ldw,
                                               const float* __restrict__ bias1, const float* __restrict__ bias2,
                                               u16* __restrict__ Cb, float* __restrict__ Cf, int ldc, int K){
  constexpr int BK=32;
  constexpr int FM=BM/32, FN=BN/32;
  __shared__ __align__(16) u16 As[BM*BK];
  __shared__ __align__(16) u16 Ws[BN*BK];
  int tid=threadIdx.x, lane=tid&63, wid=tid>>6;
  int wr=wid>>1, wc=wid&1;
  long m0=(long)blockIdx.y*BM, n0=(long)blockIdx.x*BN;
  int lr=lane&15, lk=(lane>>4)*8;
  f32x4 acc[FM][FN];
  #pragma unroll
  for (int i=0;i<FM;i++)
    #pragma unroll
    for (int j=0;j<FN;j++) acc[i][j] = (f32x4){0.f,0.f,0.f,0.f};
  for (int k0=0;k0<K;k0+=BK){
    __syncthreads();
    #pragma unroll
    for (int c=tid;c<BM*4;c+=256){
      int row=c>>2, kb=(c&3)*8;
      *(s16x8*)(As + row*BK + kb) = *(const s16x8*)(A + (m0+row)*lda + k0+kb);
    }
    #pragma unroll
    for (int c=tid;c<BN*4;c+=256){
      int row=c>>2, kb=(c&3)*8;
      *(s16x8*)(Ws + row*BK + kb) = *(const s16x8*)(W + (n0+row)*ldw + k0+kb);
    }
    __syncthreads();
    bv8 af[FM], bf[FN];
    #pragma unroll
    for (int i=0;i<FM;i++) af[i] = ldf(As + (wr*(BM/2)+i*16+lr)*BK + lk);
    #pragma unroll
    for (int j=0;j<FN;j++) bf[j] = ldf(Ws + (wc*(BN/2)+j*16+lr)*BK + lk);
    #pragma unroll
    for (int i=0;i<FM;i++)
      #pragma unroll
      for (int j=0;j<FN;j++) acc[i][j] = mfma16(af[i], bf[j], acc[i][j]);
  }
  #pragma unroll
  for (int i=0;i<FM;i++)
    #pragma unroll
    for (int j=0;j<FN;j++)
      #pragma unroll
      for (int r=0;r<4;r++){
        int m = wr*(BM/2)+i*16+(lane>>4)*4+r;
        int n = wc*(BN/2)+j*16+lr;
        float v = acc[i][j][r];
        if (bias1) v += bias1[n0+n];
        if (bias2) v += bias2[n0+n];
        if (RELU) v = fmaxf(v,0.f);
        if (OUTF32) Cf[(m0+m)*ldc + n0+n] = v;
        else        Cb[(m0+m)*ldc + n0+n] = f2b(v);
      }
}

// ---------------- one encoder LSTM step, both directions fused ----------------
// grid 128: kc=bx&7 (64-cell chunk), bt=(bx>>3)&7 (64-sample tile), dir=bx>>6
__global__ __launch_bounds__(256) void enc_step(const u16* __restrict__ xe, const int* __restrict__ lens,
    const u16* __restrict__ Wih_f, const u16* __restrict__ Whh_f, const float* __restrict__ bih_f, const float* __restrict__ bhh_f,
    const u16* __restrict__ Wih_b, const u16* __restrict__ Whh_b, const float* __restrict__ bih_b, const float* __restrict__ bhh_b,
    const u16* __restrict__ hp_f, u16* __restrict__ hn_f, float* __restrict__ c_f, float* __restrict__ a_f,
    const u16* __restrict__ hp_b, u16* __restrict__ hn_b, float* __restrict__ c_b, float* __restrict__ a_b,
    int t){
  int bx=blockIdx.x;
  int kc=bx&7, bt=(bx>>3)&7, dir=bx>>6;
  const u16 *Wih, *Whh, *hp; const float *bih, *bhh; u16* hn; float *cst, *accum;
  if (dir==0){ Wih=Wih_f; Whh=Whh_f; bih=bih_f; bhh=bhh_f; hp=hp_f; hn=hn_f; cst=c_f; accum=a_f; }
  else       { Wih=Wih_b; Whh=Whh_b; bih=bih_b; bhh=bhh_b; hp=hp_b; hn=hn_b; cst=c_b; accum=a_b; }

  __shared__ __align__(16) u16 As[64*32];
  __shared__ __align__(16) u16 Ws[256*32];
  int tid=threadIdx.x, lane=tid&63, w=tid>>6;
  int lr=lane&15, lk=(lane>>4)*8;

  int arow=tid>>2, akb=(tid&3)*8;
  int ab = bt*64 + arow;
  int len_a = lens[ab];
  int tt = (dir==0)? t : max(len_a-1-t, 0);
  const u16* xrow = xe + (size_t)ab*65536 + (size_t)tt*256;   // [B,T,256]: row b*256+t => b*65536 + t*256
  const u16* hrow = hp + (size_t)ab*512;

  f32x4 gacc[4][4];
  #pragma unroll
  for (int i=0;i<4;i++)
    #pragma unroll
    for (int g=0;g<4;g++) gacc[i][g]=(f32x4){0.f,0.f,0.f,0.f};

  for (int k0=0;k0<768;k0+=32){
    __syncthreads();
    {
      const u16* src = (k0<256)? (xrow + k0 + akb) : (hrow + (k0-256) + akb);
      *(s16x8*)(As + tid*8) = *(const s16x8*)src;
    }
    #pragma unroll
    for (int j2=0;j2<4;j2++){
      int cc = tid + 256*j2;
      int rr = cc>>2, kb=(cc&3)*8;
      int g = rr>>6, cell = rr&63;
      size_t grow = (size_t)(g*512 + kc*64 + cell);
      const u16* src = (k0<256)? (Wih + grow*256 + k0 + kb)
                               : (Whh + grow*512 + (k0-256) + kb);
      *(s16x8*)(Ws + rr*32 + kb) = *(const s16x8*)src;
    }
    __syncthreads();
    bv8 af[4], bf[4];
    #pragma unroll
    for (int i=0;i<4;i++) af[i] = ldf(As + (i*16+lr)*32 + lk);
    #pragma unroll
    for (int g=0;g<4;g++) bf[g] = ldf(Ws + (g*64 + w*16 + lr)*32 + lk);
    #pragma unroll
    for (int i=0;i<4;i++)
      #pragma unroll
      for (int g=0;g<4;g++) gacc[i][g] = mfma16(af[i], bf[g], gacc[i][g]);
  }
  int cg = kc*64 + w*16 + lr;               // global cell index [0,512)
  float b_i = bih[cg]      + bhh[cg];
  float b_f = bih[512+cg]  + bhh[512+cg];
  float b_g = bih[1024+cg] + bhh[1024+cg];
  float b_o = bih[1536+cg] + bhh[1536+cg];
  #pragma unroll
  for (int i=0;i<4;i++){
    #pragma unroll
    for (int r=0;r<4;r++){
      int m = i*16 + (lane>>4)*4 + r;
      int b = bt*64 + m;
      size_t idx = (size_t)b*512 + cg;
      if (t < lens[b]){
        float iv = sigm(gacc[i][0][r] + b_i);
        float fv = sigm(gacc[i][1][r] + b_f);
        float gv = tanhf(gacc[i][2][r] + b_g);
        float ov = sigm(gacc[i][3][r] + b_o);
        float c2 = fv*cst[idx] + iv*gv;
        float h2 = ov*tanhf(c2);
        cst[idx]=c2; hn[idx]=f2b(h2); accum[idx]+=h2;
      } else {
        hn[idx] = hp[idx];                  // carry frozen state through ping-pong
      }
    }
  }
}

// ---------------- pooled (mean over valid steps) -> bf16 [512,1024] ----------------
__global__ __launch_bounds__(256) void pool_k(const float* __restrict__ af, const float* __restrict__ ab,
                                              const int* __restrict__ lens, u16* __restrict__ pooled){
  int idx = blockIdx.x*256 + threadIdx.x;     // 524288 total
  int b = idx>>10, j = idx&1023;
  float v = (j<512? af[(size_t)b*512+j] : ab[(size_t)b*512 + (j-512)]) / (float)lens[b];
  pooled[idx] = f2b(v);
}

// ---------------- one decoder LSTM step ----------------
// grid 64: kc=bx&7, bt=bx>>3.  gates = gix + [pose | h_prev] @ [Wih_d[:,256:384] | Whh_d]^T
__global__ __launch_bounds__(256) void dec_step(const u16* __restrict__ pose,
    const u16* __restrict__ Wih_d, const u16* __restrict__ Whh_d, const float* __restrict__ gix,
    const u16* __restrict__ hp, u16* __restrict__ hn, float* __restrict__ cst){
  int bx=blockIdx.x;
  int kc=bx&7, bt=bx>>3;
  __shared__ __align__(16) u16 As[64*32];
  __shared__ __align__(16) u16 Ws[256*32];
  int tid=threadIdx.x, lane=tid&63, w=tid>>6;
  int lr=lane&15, lk=(lane>>4)*8;
  int arow=tid>>2, akb=(tid&3)*8;
  int ab = bt*64 + arow;
  const u16* prow = pose + (size_t)ab*128;
  const u16* hrow = hp + (size_t)ab*512;

  f32x4 gacc[4][4];
  #pragma unroll
  for (int i=0;i<4;i++)
    #pragma unroll
    for (int g=0;g<4;g++) gacc[i][g]=(f32x4){0.f,0.f,0.f,0.f};

  for (int k0=0;k0<640;k0+=32){
    __syncthreads();
    {
      const u16* src = (k0<128)? (prow + k0 + akb) : (hrow + (k0-128) + akb);
      *(s16x8*)(As + tid*8) = *(const s16x8*)src;
    }
    #pragma unroll
    for (int j2=0;j2<4;j2++){
      int cc = tid + 256*j2;
      int rr = cc>>2, kb=(cc&3)*8;
      int g = rr>>6, cell = rr&63;
      size_t grow = (size_t)(g*512 + kc*64 + cell);
      const u16* src = (k0<128)? (Wih_d + grow*384 + 256 + k0 + kb)
                               : (Whh_d + grow*512 + (k0-128) + kb);
      *(s16x8*)(Ws + rr*32 + kb) = *(const s16x8*)src;
    }
    __syncthreads();
    bv8 af[4], bf[4];
    #pragma unroll
    for (int i=0;i<4;i++) af[i] = ldf(As + (i*16+lr)*32 + lk);
    #pragma unroll
    for (int g=0;g<4;g++) bf[g] = ldf(Ws + (g*64 + w*16 + lr)*32 + lk);
    #pragma unroll
    for (int i=0;i<4;i++)
      #pragma unroll
      for (int g=0;g<4;g++) gacc[i][g] = mfma16(af[i], bf[g], gacc[i][g]);
  }
  int cg = kc*64 + w*16 + lr;
  #pragma unroll
  for (int i=0;i<4;i++){
    #pragma unroll
    for (int r=0;r<4;r++){
      int m = i*16 + (lane>>4)*4 + r;
      int b = bt*64 + m;
      size_t gb = (size_t)b*2048;
      float iv = sigm(gacc[i][0][r] + gix[gb + cg]);
      float fv = sigm(gacc[i][1][r] + gix[gb + 512 + cg]);
      float gv = tanhf(gacc[i][2][r] + gix[gb + 1024 + cg]);
      float ov = sigm(gacc[i][3][r] + gix[gb + 1536 + cg]);
      size_t idx = (size_t)b*512 + cg;
      float c2 = fv*cst[idx] + iv*gv;
      float h2 = ov*tanhf(c2);
      cst[idx]=c2; hn[idx]=f2b(h2);
    }
  }
}

// ---------------- decoder FFN: h_=relu(h2@W1d^T+b1d); pose=h_@W2d^T+b2d ----------------
// grid 32 (16-sample tiles). pose (bf16 feedback) + out (f32) written.
__global__ __launch_bounds__(256) void dec_ffn(const u16* __restrict__ h2,
    const u16* __restrict__ W1d, const float* __restrict__ b1d,
    const u16* __restrict__ W2d, const float* __restrict__ b2d,
    u16* __restrict__ pose, float* __restrict__ out_dec, int t){
  int bt = blockIdx.x;
  __shared__ __align__(16) u16 hA[16*32];
  __shared__ __align__(16) u16 Wl[256*32];
  __shared__ __align__(16) u16 hmid[16*256];
  int tid=threadIdx.x, lane=tid&63, w=tid>>6;
  int lr=lane&15, lk=(lane>>4)*8;

  f32x4 acc1[4];
  #pragma unroll
  for (int j=0;j<4;j++) acc1[j]=(f32x4){0.f,0.f,0.f,0.f};
  for (int k0=0;k0<512;k0+=32){
    __syncthreads();
    if (tid<64){
      int row=tid>>2, kb=(tid&3)*8;
      *(s16x8*)(hA + tid*8) = *(const s16x8*)(h2 + (size_t)(bt*16+row)*512 + k0+kb);
    }
    #pragma unroll
    for (int j2=0;j2<4;j2++){
      int cc=tid+256*j2; int rr=cc>>2, kb=(cc&3)*8;
      *(s16x8*)(Wl + rr*32 + kb) = *(const s16x8*)(W1d + (size_t)rr*512 + k0+kb);
    }
    __syncthreads();
    bv8 a = ldf(hA + lr*32 + lk);
    #pragma unroll
    for (int fn=0;fn<4;fn++){
      bv8 bb = ldf(Wl + (w*64+fn*16+lr)*32 + lk);
      acc1[fn] = mfma16(a, bb, acc1[fn]);
    }
  }
  #pragma unroll
  for (int fn=0;fn<4;fn++)
    #pragma unroll
    for (int r=0;r<4;r++){
      int m=(lane>>4)*4+r; int n=w*64+fn*16+lr;
      float v = acc1[fn][r] + b1d[n];
      hmid[m*256+n] = f2b(fmaxf(v,0.f));
    }
  __syncthreads();

  f32x4 acc2[2];
  acc2[0]=(f32x4){0.f,0.f,0.f,0.f}; acc2[1]=(f32x4){0.f,0.f,0.f,0.f};
  for (int k0=0;k0<256;k0+=32){
    __syncthreads();
    #pragma unroll
    for (int j2=0;j2<2;j2++){
      int cc=tid+256*j2; int rr=cc>>2, kb=(cc&3)*8;
      *(s16x8*)(Wl + rr*32 + kb) = *(const s16x8*)(W2d + (size_t)rr*256 + k0+kb);
    }
    __syncthreads();
    bv8 a = ldf(hmid + lr*256 + k0 + lk);
    #pragma unroll
    for (int fn=0;fn<2;fn++){
      bv8 bb = ldf(Wl + (w*32+fn*16+lr)*32 + lk);
      acc2[fn] = mfma16(a, bb, acc2[fn]);
    }
  }
  #pragma unroll
  for (int fn=0;fn<2;fn++)
    #pragma unroll
    for (int r=0;r<4;r++){
      int m=(lane>>4)*4+r; int n=w*32+fn*16+lr;
      int b = bt*16+m;
      float v = acc2[fn][r] + b2d[n];
      pose[(size_t)b*128+n] = f2b(v);
      out_dec[(size_t)b*32768 + (size_t)t*128 + n] = v;
    }
}

__global__ __launch_bounds__(512) void len_cast(const int* __restrict__ lens, float* __restrict__ out){
  int i = threadIdx.x;
  if (i < 512) out[i] = (float)lens[i];
}

// ============================== host ==============================
extern "C" void kernel_launch(void* const* d_in, const int* in_sizes, int n_in,
                              void* d_out, int out_size, void* d_ws, size_t ws_size,
                              hipStream_t stream){
  (void)in_sizes; (void)n_in; (void)out_size; (void)ws_size;
  const float* x      = (const float*)d_in[0];
  const int*   lens   = (const int*)d_in[1];
  const float* ng     = (const float*)d_in[2];
  const float* nb     = (const float*)d_in[3];
  const float* We     = (const float*)d_in[4];
  const float* be     = (const float*)d_in[5];
  const float* Wih_f  = (const float*)d_in[6];
  const float* Whh_f  = (const float*)d_in[7];
  const float* bih_f  = (const float*)d_in[8];
  const float* bhh_f  = (const float*)d_in[9];
  const float* Wih_b  = (const float*)d_in[10];
  const float* Whh_b  = (const float*)d_in[11];
  const float* bih_b  = (const float*)d_in[12];
  const float* bhh_b  = (const float*)d_in[13];
  const float* W1e    = (const float*)d_in[14];
  const float* b1e    = (const float*)d_in[15];
  const float* W2e    = (const float*)d_in[16];
  const float* b2e    = (const float*)d_in[17];
  const float* Wd     = (const float*)d_in[18];
  const float* bd     = (const float*)d_in[19];
  const float* Wp1    = (const float*)d_in[20];
  const float* bp1    = (const float*)d_in[21];
  const float* Wp2    = (const float*)d_in[22];
  const float* bp2    = (const float*)d_in[23];
  const float* Wih_d  = (const float*)d_in[24];
  const float* Whh_d  = (const float*)d_in[25];
  const float* bih_d  = (const float*)d_in[26];
  const float* bhh_d  = (const float*)d_in[27];
  const float* W1d    = (const float*)d_in[28];
  const float* b1d    = (const float*)d_in[29];
  const float* W2d    = (const float*)d_in[30];
  const float* b2d    = (const float*)d_in[31];

  char* p = (char*)d_ws;
  auto carve = [&](size_t bytes)->void*{ void* r=(void*)p; p += (bytes+255)&~(size_t)255; return r; };
  float* mu   = (float*)carve(512*4);
  float* rstd = (float*)carve(512*4);
  u16* xe     = (u16*)carve((size_t)33554432*2);     // [B*T,256] bf16
  // converted bf16 weights
  u16* wWe  = (u16*)carve(32768*2);
  u16* wIhf = (u16*)carve(524288*2);
  u16* wHhf = (u16*)carve(1048576*2);
  u16* wIhb = (u16*)carve(524288*2);
  u16* wHhb = (u16*)carve(1048576*2);
  u16* wW1e = (u16*)carve(524288*2);
  u16* wW2e = (u16*)carve(131072*2);
  u16* wWd  = (u16*)carve(65536*2);
  u16* wWp1 = (u16*)carve(65536*2);
  u16* wWp2 = (u16*)carve(32768*2);
  u16* wIhd = (u16*)carve(786432*2);
  u16* wHhd = (u16*)carve(1048576*2);
  u16* wW1d = (u16*)carve(131072*2);
  u16* wW2d = (u16*)carve(32768*2);
  u16* hf[2]  = {(u16*)carve(524288),(u16*)carve(524288)};
  u16* hb[2]  = {(u16*)carve(524288),(u16*)carve(524288)};
  u16* hd[2]  = {(u16*)carve(524288),(u16*)carve(524288)};
  float* cf   = (float*)carve(1048576);
  float* cb   = (float*)carve(1048576);
  float* cd   = (float*)carve(1048576);
  float* af   = (float*)carve(1048576);
  float* ab_  = (float*)carve(1048576);
  u16* pooled = (u16*)carve(1048576);
  u16* out1   = (u16*)carve(524288);
  u16* zlat   = (u16*)carve(262144);
  u16* x0     = (u16*)carve(262144);
  u16* t0     = (u16*)carve(262144);
  float* gix  = (float*)carve(4194304);
  u16* pose   = (u16*)carve(131072);

  float* out_x   = (float*)d_out;
  float* out_dec = out_x + 16777216;
  float* out_len = out_x + 33554432;

  // output 0: pass-through copy of x (f32); zero recurrent state
  hipMemcpyAsync(out_x, x, (size_t)16777216*4, hipMemcpyDeviceToDevice, stream);
  hipMemsetAsync(hf[0],0,524288,stream);
  hipMemsetAsync(hb[0],0,524288,stream);
  hipMemsetAsync(hd[0],0,524288,stream);
  hipMemsetAsync(cf,0,1048576,stream);
  hipMemsetAsync(cb,0,1048576,stream);
  hipMemsetAsync(cd,0,1048576,stream);
  hipMemsetAsync(af,0,1048576,stream);
  hipMemsetAsync(ab_,0,1048576,stream);

  // convert 14 weight matrices to bf16 in one launch
  CvtJobs J;
  const float* srcs[14] = {We,Wih_f,Whh_f,Wih_b,Whh_b,W1e,W2e,Wd,Wp1,Wp2,Wih_d,Whh_d,W1d,W2d};
  u16* dsts[14] = {wWe,wIhf,wHhf,wIhb,wHhb,wW1e,wW2e,wWd,wWp1,wWp2,wIhd,wHhd,wW1d,wW2d};
  int ns[14] = {32768,524288,1048576,524288,1048576,524288,131072,65536,65536,32768,786432,1048576,131072,32768};
  int blk=0;
  for (int i=0;i<14;i++){ J.s[i]=srcs[i]; J.d[i]=dsts[i]; J.start[i]=blk; blk += ns[i]/2048; }
  cvt_w<<<blk,256,0,stream>>>(J);

  // encoder front-end: LN stats, then fused LN+encode GEMM
  ln_stats<<<512,256,0,stream>>>(x,mu,rstd);
  ln_gemm<<<dim3(2,1024),256,0,stream>>>(x,mu,rstd,ng,nb,wWe,be,xe);

  // bidirectional masked LSTM (fused fwd+bwd per step)
  for (int t=0;t<256;t++){
    int pp=t&1;
    enc_step<<<128,256,0,stream>>>(xe,lens,
      wIhf,wHhf,bih_f,bhh_f, wIhb,wHhb,bih_b,bhh_b,
      hf[pp],hf[pp^1],cf,af, hb[pp],hb[pp^1],cb,ab_, t);
  }

  // pooling + latent + decoder init
  pool_k<<<2048,256,0,stream>>>(af,ab_,lens,pooled);
  gemm_bt<64,64,true ,false><<<dim3(8,8),256,0,stream>>>(pooled,1024,wW1e,1024,b1e,nullptr,out1,nullptr,512,1024);
  gemm_bt<64,64,false,false><<<dim3(4,8),256,0,stream>>>(out1,512,wW2e,512,b2e,nullptr,zlat,nullptr,256,512);
  gemm_bt<64,64,true ,false><<<dim3(4,8),256,0,stream>>>(zlat,256,wWd,256,bd,nullptr,x0,nullptr,256,256);
  gemm_bt<64,64,true ,false><<<dim3(4,8),256,0,stream>>>(x0,256,wWp1,256,bp1,nullptr,t0,nullptr,256,256);
  gemm_bt<64,64,false,false><<<dim3(2,8),256,0,stream>>>(t0,256,wWp2,256,bp2,nullptr,pose,nullptr,128,256);
  // step-invariant x0 part of decoder gates (+ both biases), f32
  gemm_bt<64,128,false,true><<<dim3(16,8),256,0,stream>>>(x0,256,wIhd,384,bih_d,bhh_d,nullptr,gix,2048,256);

  // autoregressive decoder
  for (int t=0;t<256;t++){
    int pp=t&1;
    dec_step<<<64,256,0,stream>>>(pose,wIhd,wHhd,gix,hd[pp],hd[pp^1],cd);
    dec_ffn<<<32,256,0,stream>>>(hd[pp^1],wW1d,b1d,wW2d,b2d,pose,out_dec,t);
  }

  // output 2: lengths as f32
  len_cast<<<1,512,0,stream>>>(lens,out_len);
}